// Round 26
// baseline (5604.929 us; speedup 1.0000x reference)
//
#include <hip/hip_runtime.h>
#include <hip/hip_bf16.h>

#define NTRAIN 100000
#define NBIT   64
#define NCLASS 100
#define NBATCH 128
#define NW     1563   /* ceil(100000/64) */
#define NWP    1568   /* padded stride   */
#define NP1    100001.0f
#define ETA_MU 55.0f

#define NBLK   391    /* ceil(100000/256) */
#define NLIKB  1563   /* ceil(100032/64): one block per 64 j-columns */
#define NCLB   50     /* 50*256 = 12800 = NCLASS*NBATCH */
#define NDOTB  656    /* 656*16 waves = 10496 = 4096 (BBT) + 6400 (BYT) */
#define SCAP   4096   /* slow-column list capacity */
#define SLACK  2e-5f  /* fp-rounding guard on the |p| > rowabs test */

typedef unsigned long long u64;
typedef unsigned int u32;
typedef __attribute__((ext_vector_type(8))) short bf16x8;
typedef __attribute__((ext_vector_type(4))) float f32x4;

// ---------------- workspace layout (bytes) ----------------
#define OFF_BMASK   0u                       /* u64[100000]        800000 */
#define OFF_CMASK   800000u                  /* u64[100][1568]    1254400 */
#define OFF_PLANES  2054400u                 /* u64[64][1568]      802816 */
#define OFF_LABELY  2857216u                 /* int[100000]        400000 */
#define OFF_OVR     3257216u                 /* int[100000]        400000 */
#define OFF_YLAB    3657216u                 /* int[128]              512 */
#define OFF_CCOUNT  3657728u                 /* int[100]              512 */
#define OFF_AF      3658240u                 /* f32[4096]           16384 */
#define OFF_RHS     3674624u                 /* f32[100][64]        25600 */
#define OFF_W       3700224u                 /* f32[64][100]        25600 */
#define OFF_WT      3725824u                 /* f32[100][64]        25600 */
#define OFF_G       3751424u                 /* f32[64][64]         16384 */
#define OFF_ROWABS  3767808u                 /* f32[64]               256 */
#define OFF_SCNT    3768064u                 /* int[1] (+pad)         256 */
#define OFF_SLIST   3768320u                 /* int[4096]           16384 */
#define OFF_SOLD    3784704u                 /* u64[4096]           32768 */
#define OFF_IAI     3817472u                 /* int[4096]           16384 */
#define OFF_IBI     3833856u                 /* int[6400]           25600 */
#define OFF_DCNT    3859456u                 /* int[1] (+pad)         256 */
#define OFF_DLIST   3859712u                 /* int[100000]        400000 */
#define OFF_DOLD    4259712u                 /* u64[100000]        800000 */
#define OFF_LIKP    5059712u                 /* f32[1563]            6400 */
#define OFF_CLP     5066112u                 /* f32[50]               256 */
/* total ~5.07 MB */

__device__ __forceinline__ float blk_reduce_sum(float v, float* sbuf) {
    int tid = threadIdx.x;
    for (int off = 32; off > 0; off >>= 1) v += __shfl_down(v, off, 64);
    __syncthreads();
    if ((tid & 63) == 0) sbuf[tid >> 6] = v;
    __syncthreads();
    float t = 0.f;
    if (tid == 0) {
        int nw = (int)(blockDim.x >> 6);
        for (int q = 0; q < nw; ++q) t += sbuf[q];
    }
    return t;   // valid on tid 0 only
}

__device__ __forceinline__ short f2bf(float v) {
    __hip_bfloat16 h = __float2bfloat16(v);
    return *reinterpret_cast<short*>(&h);
}

// batch labels + override table (runs FIRST); also zeroes ccount for k_prep
__global__ void k_scatter(const float* __restrict__ y, const int* __restrict__ ind,
                          int* __restrict__ ovr, int* __restrict__ ylab,
                          int* __restrict__ ccount) {
    __shared__ int cls[NBATCH], idx[NBATCH];
    int k = threadIdx.x;
    if (k < NCLASS) ccount[k] = 0;
    if (k < NBATCH) {
        int c = 0;
        for (int r = 0; r < NCLASS; ++r)
            if (y[k * NCLASS + r] > 0.5f) c = r;
        cls[k] = c; idx[k] = ind[k]; ylab[k] = c;
    }
    __syncthreads();
    if (k == 0) {
        for (int q = 0; q < NBATCH; ++q) ovr[idx[q]] = q + 1;
    }
}

// fused: label per column (Y or override), B sign-mask, cmask via wave ballots,
// class counts via LDS histogram + deterministic integer atomics
__global__ __launch_bounds__(256) void k_prep(const float* __restrict__ Y,
                                              const float* __restrict__ B,
                                              const int* __restrict__ ovr,
                                              const int* __restrict__ ylab,
                                              int* __restrict__ labelY,
                                              u64* __restrict__ Bmask,
                                              u64* __restrict__ cmask,
                                              int* __restrict__ ccount) {
    __shared__ int hist[NCLASS];
    int tid = threadIdx.x, lane = tid & 63, wid = tid >> 6;
    if (tid < NCLASS) hist[tid] = 0;
    __syncthreads();
    int w = blockIdx.x * 4 + wid;
    int j = w * 64 + lane;
    int lab = -1;
    if (j < NTRAIN) {
        lab = 0;
        for (int r = 0; r < NCLASS; ++r)
            if (Y[r * NTRAIN + j] > 0.5f) lab = r;
        int ov = ovr[j];
        if (ov) lab = ylab[ov - 1];
        labelY[j] = lab;
        u64 m = 0ull;
        #pragma unroll
        for (int i = 0; i < NBIT; ++i)
            if (B[i * NTRAIN + j] > 0.0f) m |= (1ull << i);
        Bmask[j] = m;
        atomicAdd(&hist[lab], 1);
    }
    u64 keep0 = 0ull, keep1 = 0ull;
    for (int c = 0; c < NCLASS; ++c) {
        u64 bal = __ballot(lab == c);
        if (lane == c)      keep0 = bal;
        if (lane == c - 64) keep1 = bal;
    }
    if (w < NW) {
        cmask[(size_t)lane * NWP + w] = keep0;
        if (lane < NCLASS - 64) cmask[(size_t)(lane + 64) * NWP + w] = keep1;
    }
    __syncthreads();
    if (tid < NCLASS && hist[tid]) atomicAdd(&ccount[tid], hist[tid]);
}

// column-masks -> row bitplanes (64x64 bit transpose via ballot); 391 blocks
__global__ __launch_bounds__(256) void k_trans(const u64* __restrict__ Bmask,
                                               u64* __restrict__ planes) {
    int gid = blockIdx.x * 256 + threadIdx.x;
    int w = gid >> 6, lane = threadIdx.x & 63;
    if (w >= NW) return;
    int j = w * 64 + lane;
    u64 m = (j < NTRAIN) ? Bmask[j] : 0ull;
    u64 acc = 0ull;
    #pragma unroll
    for (int i = 0; i < 64; ++i) {
        u64 bal = __ballot((m >> i) & 1ull);
        if (lane == i) acc = bal;
    }
    planes[(size_t)lane * NWP + w] = acc;
}

// one WAVE per output element of BB^T (4096) and BY^T (6400): 10496 waves over
// 656 blocks; coalesced 512B loads (planes+cmask L2-resident). Writes
// A_f/RHS_f AND raw ints (seed for the incremental chain). Exact integer math.
__global__ __launch_bounds__(1024) void k_dot(const u64* __restrict__ planes,
                                              const u64* __restrict__ cmask,
                                              const int* __restrict__ ccount,
                                              float* __restrict__ A_f,
                                              float* __restrict__ RHS_f,
                                              int* __restrict__ iAint,
                                              int* __restrict__ iBint) {
    int tid = threadIdx.x, lane = tid & 63, wv = tid >> 6;
    int wg = blockIdx.x * 16 + wv;     /* 0..10495 */
    int s = 0;
    if (wg < 4096) {
        int i = wg >> 6, l = wg & 63;
        const u64* __restrict__ Pi = planes + (size_t)i * NWP;
        const u64* __restrict__ Pl = planes + (size_t)l * NWP;
        for (int w = lane; w < NW; w += 64)
            s += __popcll(Pi[w] ^ Pl[w]);
    } else {
        int idx = wg - 4096;
        int c = idx >> 6, k = idx & 63;
        const u64* __restrict__ Pk = planes + (size_t)k * NWP;
        const u64* __restrict__ Cc = cmask + (size_t)c * NWP;
        for (int w = lane; w < NW; w += 64)
            s += __popcll(Pk[w] & Cc[w]);
    }
    s += __shfl_xor(s, 1);  s += __shfl_xor(s, 2);
    s += __shfl_xor(s, 4);  s += __shfl_xor(s, 8);
    s += __shfl_xor(s, 16); s += __shfl_xor(s, 32);
    if (lane == 0) {
        if (wg < 4096) {
            int i = wg >> 6, l = wg & 63;
            iAint[wg] = s;
            A_f[wg] = (i == l) ? 0.0f
                               : (float)(NTRAIN - 2 * s) * (1.0f / NP1);
        } else {
            int idx = wg - 4096;
            iBint[idx] = s;
            RHS_f[idx] = (float)(2 * s - ccount[idx >> 6]);
        }
    }
}

// ---------------- incremental A/RHS (EXACT integer math; CHAINED) ------------
// B changed in only the dlist columns since the last full/incremental count.
// Updates iAint/iBint IN PLACE (each element owned by one thread) so the next
// pass can apply its own delta on top — replaces trans+dot for passes 2 AND 3.
__global__ __launch_bounds__(256) void k_incr(const int* __restrict__ dcnt,
                                              const int* __restrict__ dlist,
                                              const u64* __restrict__ dold,
                                              const u64* __restrict__ Bmask,
                                              const int* __restrict__ labelY,
                                              int* __restrict__ iAint,
                                              int* __restrict__ iBint,
                                              const int* __restrict__ ccount,
                                              float* __restrict__ A_f,
                                              float* __restrict__ RHS_f) {
    __shared__ u64 sn[512], so[512];
    __shared__ int sl[512];
    int tid = threadIdx.x;
    int e = blockIdx.x * 256 + tid;      /* 41 blocks -> e < 10496 */
    int n = *dcnt; if (n > NTRAIN) n = NTRAIN;
    int isA = (e < 4096);
    int i_, l_, c_;
    if (isA) { i_ = e >> 6; l_ = e & 63; }
    else     { int idx = e - 4096; c_ = idx >> 6; i_ = idx & 63; l_ = 0; }
    int dA = 0;
    for (int base = 0; base < n; base += 512) {
        int cnt = n - base; if (cnt > 512) cnt = 512;
        for (int t = tid; t < cnt; t += 256) {
            int j = dlist[base + t];
            sn[t] = Bmask[j];
            so[t] = dold[base + t];
            sl[t] = labelY[j];
        }
        __syncthreads();
        if (isA) {
            for (int t = 0; t < cnt; ++t) {
                u64 nm = sn[t], om = so[t];
                dA += (int)(((nm >> i_) ^ (nm >> l_)) & 1ull)
                    - (int)(((om >> i_) ^ (om >> l_)) & 1ull);
            }
        } else if (e < 10496) {
            for (int t = 0; t < cnt; ++t) {
                if (sl[t] == c_) {
                    dA += (int)((sn[t] >> i_) & 1ull)
                        - (int)((so[t] >> i_) & 1ull);
                }
            }
        }
        __syncthreads();
    }
    if (isA) {
        int s = iAint[e] + dA;
        iAint[e] = s;
        A_f[e] = (i_ == l_) ? 0.0f : (float)(NTRAIN - 2 * s) * (1.0f / NP1);
    } else if (e < 10496) {
        int idx = e - 4096;
        int s = iBint[idx] + dA;
        iBint[idx] = s;
        RHS_f[idx] = (float)(2 * s - ccount[c_]);
    }
}

// per-column Neumann solve: x <- v - A x (4 matvecs, ||A||~0.05)
__global__ __launch_bounds__(256) void k_wsolve(const float* __restrict__ A_f,
                                                const float* __restrict__ RHS_f,
                                                float* __restrict__ W_g,
                                                float* __restrict__ WT_g) {
    __shared__ float As[64 * 65];
    __shared__ float xb[4][64];
    int tid = threadIdx.x, lane = tid & 63, wid = tid >> 6;
    for (int e = tid; e < 4096; e += 256)
        As[(e >> 6) * 65 + (e & 63)] = A_f[e];
    int c = blockIdx.x * 4 + wid;
    float v = RHS_f[c * 64 + lane];
    float x = v;
    __syncthreads();
    for (int it = 0; it < 4; ++it) {
        xb[wid][lane] = x;
        __syncthreads();
        const float* __restrict__ Ar = As + lane * 65;
        const float* __restrict__ xv = xb[wid];
        float a0 = 0, a1 = 0, a2 = 0, a3 = 0;
        #pragma unroll 8
        for (int k = 0; k < 64; k += 4) {
            a0 = fmaf(Ar[k],     xv[k],     a0);
            a1 = fmaf(Ar[k + 1], xv[k + 1], a1);
            a2 = fmaf(Ar[k + 2], xv[k + 2], a2);
            a3 = fmaf(Ar[k + 3], xv[k + 3], a3);
        }
        x = v - ((a0 + a1) + (a2 + a3));
        __syncthreads();
    }
    float w = x * (1.0f / NP1);
    W_g[lane * 100 + c] = w;
    WT_g[c * 64 + lane] = w;
}

// G = W W^T (zero diag) + rowabs; zeroes scnt AND dcnt
__global__ __launch_bounds__(256) void k_gram(const float* __restrict__ WT,
                                              float* __restrict__ G_g,
                                              float* __restrict__ rowabs,
                                              int* __restrict__ scnt,
                                              int* __restrict__ dcnt) {
    __shared__ float WTs[6400];
    int tid = threadIdx.x;
    for (int e = tid; e < 6400; e += 256) WTs[e] = WT[e];
    __syncthreads();
    int e = blockIdx.x * 256 + tid;
    int k = e >> 6, l = e & 63;
    float a0 = 0, a1 = 0;
    #pragma unroll 10
    for (int c = 0; c < 100; c += 2) {
        a0 = fmaf(WTs[c * 64 + k],       WTs[c * 64 + l],       a0);
        a1 = fmaf(WTs[(c + 1) * 64 + k], WTs[(c + 1) * 64 + l], a1);
    }
    float g = (k == l) ? 0.0f : (a0 + a1);
    G_g[e] = g;
    float v = fabsf(g);
    for (int off = 32; off > 0; off >>= 1) v += __shfl_down(v, off, 64);
    if ((tid & 63) == 0) rowabs[k] = v;
    if (blockIdx.x == 0 && tid == 0) { *scnt = 0; *dcnt = 0; }
}

// ---------------- fast scan: B = sign(p), flag |p|<=rowabs columns ----------------
// EXACT for unflagged columns. track!=0: record changed columns for k_incr.
__global__ __launch_bounds__(256) void k_fast(const float* __restrict__ U,
                                              const float* __restrict__ u,
                                              const int* __restrict__ labelY,
                                              const int* __restrict__ ovr,
                                              const float* __restrict__ WT,
                                              const float* __restrict__ rowabs,
                                              u64* __restrict__ Bmask,
                                              int* __restrict__ slist,
                                              u64* __restrict__ sold,
                                              int* __restrict__ scnt,
                                              int track,
                                              int* __restrict__ dlist,
                                              u64* __restrict__ dold,
                                              int* __restrict__ dcnt) {
    __shared__ float WTs[100 * 65];   /* 65-pad: lane-varying c -> conflict-free */
    __shared__ float ra[64];
    int tid = threadIdx.x;
    for (int e = tid; e < 6400; e += 256)
        WTs[(e >> 6) * 65 + (e & 63)] = WT[e];
    if (tid < 64) ra[tid] = rowabs[tid] + SLACK;
    __syncthreads();
    int j = blockIdx.x * 256 + tid;
    if (j >= NTRAIN) return;
    int c = labelY[j], ov = ovr[j];
    const float* up; int str;
    if (ov) { up = u + (ov - 1) * NBIT; str = 1; }
    else    { up = U + j;               str = NTRAIN; }
    const float* wc = WTs + c * 65;
    u64 m = 0ull;
    int slow = 0;
    #pragma unroll
    for (int i = 0; i < NBIT; ++i) {
        float p = fmaf(ETA_MU, up[i * str], wc[i]);
        if (p > 0.0f) m |= (1ull << i);
        slow |= (fabsf(p) <= ra[i]);
    }
    if (slow) {
        int idx = atomicAdd(scnt, 1);
        if (idx < SCAP) { slist[idx] = j; sold[idx] = Bmask[j]; }
    }
    if (track) {
        u64 oldm = Bmask[j];
        if (m != oldm || slow) {
            int s2 = atomicAdd(dcnt, 1);
            dlist[s2] = j;
            dold[s2] = oldm;
        }
    }
    Bmask[j] = m;   // fallback for (impossible) list overflow; exact otherwise
}

// ---------------- wave-cooperative exact scan for flagged columns -------------
__global__ __launch_bounds__(1024) void k_slow(const int* __restrict__ slist,
                                               const u64* __restrict__ sold,
                                               const int* __restrict__ scnt,
                                               const int* __restrict__ labelY,
                                               const int* __restrict__ ovr,
                                               const float* __restrict__ G_g,
                                               const float* __restrict__ WT,
                                               const float* __restrict__ U,
                                               const float* __restrict__ u,
                                               u64* __restrict__ Bmask) {
    __shared__ float Gs[64 * 65];
    int tid = threadIdx.x, lane = tid & 63, wv = tid >> 6;   /* 16 waves */
    int n = *scnt; if (n > SCAP) n = SCAP;
    if (n == 0) return;
    for (int e = tid; e < 4096; e += 1024)
        Gs[(e >> 6) * 65 + (e & 63)] = G_g[e];
    __syncthreads();
    for (int idx = wv; idx < n; idx += 16) {
        int j = slist[idx];
        u64 m0 = sold[idx];
        int c = labelY[j], ov = ovr[j];
        float uval = ov ? u[(ov - 1) * NBIT + lane]
                        : U[(size_t)lane * NTRAIN + j];
        float p = fmaf(ETA_MU, uval, WT[c * 64 + lane]);
        float s = ((m0 >> lane) & 1ull) ? 1.0f : -1.0f;
        for (int i = 0; i < 64; ++i) {
            float t = Gs[i * 65 + lane] * s;   /* G[i,i]=0 -> self term drops */
            t += __shfl_xor(t, 1);  t += __shfl_xor(t, 2);
            t += __shfl_xor(t, 4);  t += __shfl_xor(t, 8);
            t += __shfl_xor(t, 16); t += __shfl_xor(t, 32);
            float nv = ((p - t) > 0.0f) ? 1.0f : -1.0f;
            s = (lane == i) ? nv : s;
        }
        u64 mo = __ballot(s > 0.0f);
        if (lane == 0) Bmask[j] = mo;
    }
}

// ---------------- likelihood via MFMA (the dot-product IS a GEMM) -------------
__global__ __launch_bounds__(256) void k_likm(const float* __restrict__ U,
                                              const float* __restrict__ u,
                                              const int* __restrict__ labelY,
                                              const int* __restrict__ ovr,
                                              const int* __restrict__ ylab,
                                              float* __restrict__ partials) {
    __shared__ short ubf[128 * 72];
    __shared__ int ylab_s[NBATCH];
    __shared__ float sbuf[8];
    int tid = threadIdx.x;
    for (int e = tid; e < NBATCH * NBIT; e += 256)
        ubf[(e >> 6) * 72 + (e & 63)] = f2bf(u[e]);
    if (tid < NBATCH) ylab_s[tid] = ylab[tid];
    __syncthreads();
    int w = tid >> 6, lane = tid & 63;
    int g = lane >> 4, c = lane & 15;
    int j = blockIdx.x * 64 + w * 16 + c;
    int jl = (j < NTRAIN) ? j : (NTRAIN - 1);
    int ov = ovr[jl];
    int lab = labelY[jl];
    const float* colp; int cstr;
    if (ov) { colp = u + (ov - 1) * NBIT; cstr = 1; }
    else    { colp = U + jl;              cstr = NTRAIN; }
    bf16x8 bf0, bf1;
    #pragma unroll
    for (int i = 0; i < 8; ++i) {
        bf0[i] = f2bf(colp[(g * 8 + i) * cstr]);
        bf1[i] = f2bf(colp[(32 + g * 8 + i) * cstr]);
    }
    float acc = 0.0f;
    #pragma unroll
    for (int bt = 0; bt < 8; ++bt) {
        bf16x8 a0 = *reinterpret_cast<const bf16x8*>(&ubf[(bt * 16 + c) * 72 + g * 8]);
        bf16x8 a1 = *reinterpret_cast<const bf16x8*>(&ubf[(bt * 16 + c) * 72 + 32 + g * 8]);
        f32x4 d = {0.f, 0.f, 0.f, 0.f};
        d = __builtin_amdgcn_mfma_f32_16x16x32_bf16(a0, bf0, d, 0, 0, 0);
        d = __builtin_amdgcn_mfma_f32_16x16x32_bf16(a1, bf1, d, 0, 0, 0);
        #pragma unroll
        for (int r = 0; r < 4; ++r) {
            int b = bt * 16 + g * 4 + r;
            float ipv = 0.5f * d[r];
            float aip = fabsf(ipv);
            float t = __logf(1.0f + __expf(-aip)) + fmaxf(ipv, 0.0f);
            if (ylab_s[b] == lab) t -= ipv;
            acc += t;
        }
    }
    if (j >= NTRAIN) acc = 0.0f;
    float tot = blk_reduce_sum(acc, sbuf);
    if (tid == 0) partials[blockIdx.x] = tot;
}

// ---------------- cl-loss, parallel: one thread per (c,b) element -------------
__global__ __launch_bounds__(256) void k_cl(const float* __restrict__ WT,
                                            const u64* __restrict__ Bmask,
                                            const int* __restrict__ ind,
                                            const float* __restrict__ y,
                                            float* __restrict__ clp) {
    __shared__ float sbuf[8];
    __shared__ u64 mB[NBATCH];
    int tid = threadIdx.x;
    if (tid < NBATCH) mB[tid] = Bmask[ind[tid]];
    __syncthreads();
    int e = blockIdx.x * 256 + tid;       /* e < 12800 exactly */
    int b = e & 127, c = e >> 7;
    u64 m = mB[b];
    const float4* __restrict__ wr = (const float4*)(WT + c * 64);
    float d0 = 0.f, d1 = 0.f, d2 = 0.f, d3 = 0.f;
    #pragma unroll
    for (int q = 0; q < 16; ++q) {
        float4 w4 = wr[q];
        int kb = q << 2;
        d0 += ((m >> kb) & 1ull)       ? w4.x : -w4.x;
        d1 += ((m >> (kb + 1)) & 1ull) ? w4.y : -w4.y;
        d2 += ((m >> (kb + 2)) & 1ull) ? w4.z : -w4.z;
        d3 += ((m >> (kb + 3)) & 1ull) ? w4.w : -w4.w;
    }
    float d = (d0 + d1) + (d2 + d3);
    float diff = y[b * NCLASS + c] - d;
    float tot = blk_reduce_sum(diff * diff, sbuf);
    if (tid == 0) clp[blockIdx.x] = tot;
}

// ---------------- final combine: lik partials + cl partials + reg loss --------
__global__ void k_fin(const float* __restrict__ WT,
                      const float* __restrict__ likp,
                      const float* __restrict__ clp,
                      float* __restrict__ out) {
    __shared__ float sbuf[8];
    int tid = threadIdx.x;
    float a = 0.f;
    for (int i = tid; i < NLIKB; i += 256) a += likp[i];
    float cl = 0.f;
    for (int i = tid; i < NCLB; i += 256) cl += clp[i];
    float rg = 0.f;
    for (int e = tid; e < NBIT * NCLASS; e += 256) {
        float w = WT[e];
        rg = fmaf(w, w, rg);
    }
    float lik = blk_reduce_sum(a, sbuf);
    float clS = blk_reduce_sum(cl, sbuf);
    float rgS = blk_reduce_sum(rg, sbuf);
    if (tid == 0) {
        out[0] = lik * (1.0f / ((float)NBATCH * (float)NTRAIN))
               + clS * (1.0f / (float)(NCLASS * NBATCH))
               + rgS * (1.0f / (float)(NBIT * NCLASS));
    }
}

extern "C" void kernel_launch(void* const* d_in, const int* in_sizes, int n_in,
                              void* d_out, int out_size, void* d_ws, size_t ws_size,
                              hipStream_t stream) {
    const float* u   = (const float*)d_in[0];
    const float* y   = (const float*)d_in[1];
    const float* U   = (const float*)d_in[2];
    const float* B   = (const float*)d_in[3];
    const float* Y   = (const float*)d_in[4];
    const int*   ind = (const int*)d_in[5];

    char* ws = (char*)d_ws;
    u64*   Bmask  = (u64*)(ws + OFF_BMASK);
    u64*   cmask  = (u64*)(ws + OFF_CMASK);
    u64*   planes = (u64*)(ws + OFF_PLANES);
    int*   labelY = (int*)(ws + OFF_LABELY);
    int*   ovr    = (int*)(ws + OFF_OVR);
    int*   ylab   = (int*)(ws + OFF_YLAB);
    int*   ccount = (int*)(ws + OFF_CCOUNT);
    float* A_f    = (float*)(ws + OFF_AF);
    float* RHS_f  = (float*)(ws + OFF_RHS);
    float* W      = (float*)(ws + OFF_W);
    float* WT     = (float*)(ws + OFF_WT);
    float* G      = (float*)(ws + OFF_G);
    float* rowabs = (float*)(ws + OFF_ROWABS);
    int*   scnt   = (int*)(ws + OFF_SCNT);
    int*   slist  = (int*)(ws + OFF_SLIST);
    u64*   sold   = (u64*)(ws + OFF_SOLD);
    int*   iAint  = (int*)(ws + OFF_IAI);
    int*   iBint  = (int*)(ws + OFF_IBI);
    int*   dcnt   = (int*)(ws + OFF_DCNT);
    int*   dlist  = (int*)(ws + OFF_DLIST);
    u64*   dold   = (u64*)(ws + OFF_DOLD);
    float* likp   = (float*)(ws + OFF_LIKP);
    float* clp    = (float*)(ws + OFF_CLP);

    hipMemsetAsync(ovr, 0, NTRAIN * sizeof(int), stream);

    k_scatter<<<1, 128, 0, stream>>>(y, ind, ovr, ylab, ccount);
    k_prep   <<<NBLK, 256, 0, stream>>>(Y, B, ovr, ylab, labelY, Bmask, cmask, ccount);

    // pass 1: full BBT/BYT via transpose + dot (seeds the integer counts).
    // k_gram zeroes dcnt BEFORE k_fast appends, every pass.
    k_trans  <<<NBLK, 256, 0, stream>>>(Bmask, planes);
    k_dot    <<<NDOTB, 1024, 0, stream>>>(planes, cmask, ccount,
                                          A_f, RHS_f, iAint, iBint);
    k_wsolve <<<25, 256, 0, stream>>>(A_f, RHS_f, W, WT);
    k_gram   <<<16, 256, 0, stream>>>(WT, G, rowabs, scnt, dcnt);
    k_fast   <<<NBLK, 256, 0, stream>>>(U, u, labelY, ovr, WT, rowabs,
                                        Bmask, slist, sold, scnt,
                                        1, dlist, dold, dcnt);
    k_slow   <<<1, 1024, 0, stream>>>(slist, sold, scnt, labelY, ovr,
                                      G, WT, U, u, Bmask);

    // pass 2: incremental counts (chained; k_incr updates iAint/iBint in place)
    k_incr  <<<41, 256, 0, stream>>>(dcnt, dlist, dold, Bmask, labelY,
                                     iAint, iBint, ccount, A_f, RHS_f);
    k_wsolve<<<25, 256, 0, stream>>>(A_f, RHS_f, W, WT);
    k_gram  <<<16, 256, 0, stream>>>(WT, G, rowabs, scnt, dcnt);
    k_fast  <<<NBLK, 256, 0, stream>>>(U, u, labelY, ovr, WT, rowabs,
                                       Bmask, slist, sold, scnt,
                                       1, dlist, dold, dcnt);
    k_slow  <<<1, 1024, 0, stream>>>(slist, sold, scnt, labelY, ovr,
                                     G, WT, U, u, Bmask);

    // pass 3: incremental again
    k_incr  <<<41, 256, 0, stream>>>(dcnt, dlist, dold, Bmask, labelY,
                                     iAint, iBint, ccount, A_f, RHS_f);
    k_wsolve<<<25, 256, 0, stream>>>(A_f, RHS_f, W, WT);
    k_gram  <<<16, 256, 0, stream>>>(WT, G, rowabs, scnt, dcnt);
    k_fast  <<<NBLK, 256, 0, stream>>>(U, u, labelY, ovr, WT, rowabs,
                                       Bmask, slist, sold, scnt,
                                       0, dlist, dold, dcnt);
    k_slow  <<<1, 1024, 0, stream>>>(slist, sold, scnt, labelY, ovr,
                                     G, WT, U, u, Bmask);

    k_likm <<<NLIKB, 256, 0, stream>>>(U, u, labelY, ovr, ylab, likp);
    k_cl   <<<NCLB, 256, 0, stream>>>(WT, Bmask, ind, y, clp);
    k_fin  <<<1, 256, 0, stream>>>(WT, likp, clp, (float*)d_out);
}

// Round 27
// 229.513 us; speedup vs baseline: 24.4210x; 24.4210x over previous
//
#include <hip/hip_runtime.h>
#include <hip/hip_bf16.h>

#define NTRAIN 100000
#define NBIT   64
#define NCLASS 100
#define NBATCH 128
#define NW     1563   /* ceil(100000/64) */
#define NWP    1568   /* padded stride   */
#define NP1    100001.0f
#define ETA_MU 55.0f

#define NBLK   391    /* ceil(100000/256) */
#define NLIKB  1563   /* ceil(100032/64): one block per 64 j-columns */
#define NCLB   50     /* 50*256 = 12800 = NCLASS*NBATCH */
#define NDOTB  656    /* 656*16 waves = 10496 = 4096 (BBT) + 6400 (BYT) */
#define SCAP   4096   /* slow-column list capacity */
#define SLACK  2e-5f  /* fp-rounding guard on the |p| > rowabs test */

typedef unsigned long long u64;
typedef unsigned int u32;
typedef __attribute__((ext_vector_type(8))) short bf16x8;
typedef __attribute__((ext_vector_type(4))) float f32x4;

// ---------------- workspace layout (bytes) ----------------
#define OFF_BMASK   0u                       /* u64[100000]        800000 */
#define OFF_CMASK   800000u                  /* u64[100][1568]    1254400 */
#define OFF_PLANES  2054400u                 /* u64[64][1568]      802816 */
#define OFF_LABELY  2857216u                 /* int[100000]        400000 */
#define OFF_OVR     3257216u                 /* int[100000]        400000 */
#define OFF_YLAB    3657216u                 /* int[128]              512 */
#define OFF_CCOUNT  3657728u                 /* int[100]              512 */
#define OFF_AF      3658240u                 /* f32[4096]           16384 */
#define OFF_RHS     3674624u                 /* f32[100][64]        25600 */
#define OFF_W       3700224u                 /* f32[64][100]        25600 */
#define OFF_WT      3725824u                 /* f32[100][64]        25600 */
#define OFF_G       3751424u                 /* f32[64][64]         16384 */
#define OFF_ROWABS  3767808u                 /* f32[64]               256 */
#define OFF_SCNT    3768064u                 /* int[1] (+pad)         256 */
#define OFF_SLIST   3768320u                 /* int[4096]           16384 */
#define OFF_SOLD    3784704u                 /* u64[4096]           32768 */
#define OFF_IAI     3817472u                 /* int[4096]           16384 */
#define OFF_IBI     3833856u                 /* int[6400]           25600 */
#define OFF_DCNT    3859456u                 /* int[1] (+pad)         256 */
#define OFF_DLIST   3859712u                 /* int[100000]        400000 */
#define OFF_DOLD    4259712u                 /* u64[100000]        800000 */
#define OFF_LIKP    5059712u                 /* f32[1563]            6400 */
#define OFF_CLP     5066112u                 /* f32[50]               256 */
/* total ~5.07 MB */

__device__ __forceinline__ float blk_reduce_sum(float v, float* sbuf) {
    int tid = threadIdx.x;
    for (int off = 32; off > 0; off >>= 1) v += __shfl_down(v, off, 64);
    __syncthreads();
    if ((tid & 63) == 0) sbuf[tid >> 6] = v;
    __syncthreads();
    float t = 0.f;
    if (tid == 0) {
        int nw = (int)(blockDim.x >> 6);
        for (int q = 0; q < nw; ++q) t += sbuf[q];
    }
    return t;   // valid on tid 0 only
}

__device__ __forceinline__ short f2bf(float v) {
    __hip_bfloat16 h = __float2bfloat16(v);
    return *reinterpret_cast<short*>(&h);
}

// batch labels + override table (runs FIRST); also zeroes ccount for k_prep
__global__ void k_scatter(const float* __restrict__ y, const int* __restrict__ ind,
                          int* __restrict__ ovr, int* __restrict__ ylab,
                          int* __restrict__ ccount) {
    __shared__ int cls[NBATCH], idx[NBATCH];
    int k = threadIdx.x;
    if (k < NCLASS) ccount[k] = 0;
    if (k < NBATCH) {
        int c = 0;
        for (int r = 0; r < NCLASS; ++r)
            if (y[k * NCLASS + r] > 0.5f) c = r;
        cls[k] = c; idx[k] = ind[k]; ylab[k] = c;
    }
    __syncthreads();
    if (k == 0) {
        for (int q = 0; q < NBATCH; ++q) ovr[idx[q]] = q + 1;
    }
}

// fused: label per column (Y or override), B sign-mask, cmask via wave ballots,
// class counts via LDS histogram + deterministic integer atomics
__global__ __launch_bounds__(256) void k_prep(const float* __restrict__ Y,
                                              const float* __restrict__ B,
                                              const int* __restrict__ ovr,
                                              const int* __restrict__ ylab,
                                              int* __restrict__ labelY,
                                              u64* __restrict__ Bmask,
                                              u64* __restrict__ cmask,
                                              int* __restrict__ ccount) {
    __shared__ int hist[NCLASS];
    int tid = threadIdx.x, lane = tid & 63, wid = tid >> 6;
    if (tid < NCLASS) hist[tid] = 0;
    __syncthreads();
    int w = blockIdx.x * 4 + wid;
    int j = w * 64 + lane;
    int lab = -1;
    if (j < NTRAIN) {
        lab = 0;
        for (int r = 0; r < NCLASS; ++r)
            if (Y[r * NTRAIN + j] > 0.5f) lab = r;
        int ov = ovr[j];
        if (ov) lab = ylab[ov - 1];
        labelY[j] = lab;
        u64 m = 0ull;
        #pragma unroll
        for (int i = 0; i < NBIT; ++i)
            if (B[i * NTRAIN + j] > 0.0f) m |= (1ull << i);
        Bmask[j] = m;
        atomicAdd(&hist[lab], 1);
    }
    u64 keep0 = 0ull, keep1 = 0ull;
    for (int c = 0; c < NCLASS; ++c) {
        u64 bal = __ballot(lab == c);
        if (lane == c)      keep0 = bal;
        if (lane == c - 64) keep1 = bal;
    }
    if (w < NW) {
        cmask[(size_t)lane * NWP + w] = keep0;
        if (lane < NCLASS - 64) cmask[(size_t)(lane + 64) * NWP + w] = keep1;
    }
    __syncthreads();
    if (tid < NCLASS && hist[tid]) atomicAdd(&ccount[tid], hist[tid]);
}

// column-masks -> row bitplanes (64x64 bit transpose via ballot); 391 blocks
__global__ __launch_bounds__(256) void k_trans(const u64* __restrict__ Bmask,
                                               u64* __restrict__ planes) {
    int gid = blockIdx.x * 256 + threadIdx.x;
    int w = gid >> 6, lane = threadIdx.x & 63;
    if (w >= NW) return;
    int j = w * 64 + lane;
    u64 m = (j < NTRAIN) ? Bmask[j] : 0ull;
    u64 acc = 0ull;
    #pragma unroll
    for (int i = 0; i < 64; ++i) {
        u64 bal = __ballot((m >> i) & 1ull);
        if (lane == i) acc = bal;
    }
    planes[(size_t)lane * NWP + w] = acc;
}

// one WAVE per output element of BB^T (4096) and BY^T (6400): 10496 waves over
// 656 blocks; coalesced 512B loads (planes+cmask L2-resident). Writes
// A_f/RHS_f AND raw ints (seed for pass-3's incremental). Exact integer math.
__global__ __launch_bounds__(1024) void k_dot(const u64* __restrict__ planes,
                                              const u64* __restrict__ cmask,
                                              const int* __restrict__ ccount,
                                              float* __restrict__ A_f,
                                              float* __restrict__ RHS_f,
                                              int* __restrict__ iAint,
                                              int* __restrict__ iBint) {
    int tid = threadIdx.x, lane = tid & 63, wv = tid >> 6;
    int wg = blockIdx.x * 16 + wv;     /* 0..10495 */
    int s = 0;
    if (wg < 4096) {
        int i = wg >> 6, l = wg & 63;
        const u64* __restrict__ Pi = planes + (size_t)i * NWP;
        const u64* __restrict__ Pl = planes + (size_t)l * NWP;
        for (int w = lane; w < NW; w += 64)
            s += __popcll(Pi[w] ^ Pl[w]);
    } else {
        int idx = wg - 4096;
        int c = idx >> 6, k = idx & 63;
        const u64* __restrict__ Pk = planes + (size_t)k * NWP;
        const u64* __restrict__ Cc = cmask + (size_t)c * NWP;
        for (int w = lane; w < NW; w += 64)
            s += __popcll(Pk[w] & Cc[w]);
    }
    s += __shfl_xor(s, 1);  s += __shfl_xor(s, 2);
    s += __shfl_xor(s, 4);  s += __shfl_xor(s, 8);
    s += __shfl_xor(s, 16); s += __shfl_xor(s, 32);
    if (lane == 0) {
        if (wg < 4096) {
            int i = wg >> 6, l = wg & 63;
            iAint[wg] = s;
            A_f[wg] = (i == l) ? 0.0f
                               : (float)(NTRAIN - 2 * s) * (1.0f / NP1);
        } else {
            int idx = wg - 4096;
            iBint[idx] = s;
            RHS_f[idx] = (float)(2 * s - ccount[idx >> 6]);
        }
    }
}

// ---------------- incremental A/RHS for pass 3 ONLY (EXACT integer math) -----
// r26 lesson: valid only when the delta list is tiny. Pass 1 changes ~ALL
// columns (initial B is random vs sign(p)), so passes 1-2 must use full
// trans+dot; only pass 2->3 has ~tens of changed columns.
__global__ __launch_bounds__(256) void k_incr(const int* __restrict__ dcnt,
                                              const int* __restrict__ dlist,
                                              const u64* __restrict__ dold,
                                              const u64* __restrict__ Bmask,
                                              const int* __restrict__ labelY,
                                              int* __restrict__ iAint,
                                              int* __restrict__ iBint,
                                              const int* __restrict__ ccount,
                                              float* __restrict__ A_f,
                                              float* __restrict__ RHS_f) {
    __shared__ u64 sn[512], so[512];
    __shared__ int sl[512];
    int tid = threadIdx.x;
    int e = blockIdx.x * 256 + tid;      /* 41 blocks -> e < 10496 */
    int n = *dcnt; if (n > NTRAIN) n = NTRAIN;
    int isA = (e < 4096);
    int i_, l_, c_;
    if (isA) { i_ = e >> 6; l_ = e & 63; }
    else     { int idx = e - 4096; c_ = idx >> 6; i_ = idx & 63; l_ = 0; }
    int dA = 0;
    for (int base = 0; base < n; base += 512) {
        int cnt = n - base; if (cnt > 512) cnt = 512;
        for (int t = tid; t < cnt; t += 256) {
            int j = dlist[base + t];
            sn[t] = Bmask[j];
            so[t] = dold[base + t];
            sl[t] = labelY[j];
        }
        __syncthreads();
        if (isA) {
            for (int t = 0; t < cnt; ++t) {
                u64 nm = sn[t], om = so[t];
                dA += (int)(((nm >> i_) ^ (nm >> l_)) & 1ull)
                    - (int)(((om >> i_) ^ (om >> l_)) & 1ull);
            }
        } else if (e < 10496) {
            for (int t = 0; t < cnt; ++t) {
                if (sl[t] == c_) {
                    dA += (int)((sn[t] >> i_) & 1ull)
                        - (int)((so[t] >> i_) & 1ull);
                }
            }
        }
        __syncthreads();
    }
    if (isA) {
        int s = iAint[e] + dA;
        A_f[e] = (i_ == l_) ? 0.0f : (float)(NTRAIN - 2 * s) * (1.0f / NP1);
    } else if (e < 10496) {
        int idx = e - 4096;
        int s = iBint[idx] + dA;
        RHS_f[idx] = (float)(2 * s - ccount[c_]);
    }
}

// per-column Neumann solve: x <- v - A x (4 matvecs, ||A||~0.05)
__global__ __launch_bounds__(256) void k_wsolve(const float* __restrict__ A_f,
                                                const float* __restrict__ RHS_f,
                                                float* __restrict__ W_g,
                                                float* __restrict__ WT_g) {
    __shared__ float As[64 * 65];
    __shared__ float xb[4][64];
    int tid = threadIdx.x, lane = tid & 63, wid = tid >> 6;
    for (int e = tid; e < 4096; e += 256)
        As[(e >> 6) * 65 + (e & 63)] = A_f[e];
    int c = blockIdx.x * 4 + wid;
    float v = RHS_f[c * 64 + lane];
    float x = v;
    __syncthreads();
    for (int it = 0; it < 4; ++it) {
        xb[wid][lane] = x;
        __syncthreads();
        const float* __restrict__ Ar = As + lane * 65;
        const float* __restrict__ xv = xb[wid];
        float a0 = 0, a1 = 0, a2 = 0, a3 = 0;
        #pragma unroll 8
        for (int k = 0; k < 64; k += 4) {
            a0 = fmaf(Ar[k],     xv[k],     a0);
            a1 = fmaf(Ar[k + 1], xv[k + 1], a1);
            a2 = fmaf(Ar[k + 2], xv[k + 2], a2);
            a3 = fmaf(Ar[k + 3], xv[k + 3], a3);
        }
        x = v - ((a0 + a1) + (a2 + a3));
        __syncthreads();
    }
    float w = x * (1.0f / NP1);
    W_g[lane * 100 + c] = w;
    WT_g[c * 64 + lane] = w;
}

// G = W W^T (zero diag) + rowabs; zeroes scnt AND dcnt
__global__ __launch_bounds__(256) void k_gram(const float* __restrict__ WT,
                                              float* __restrict__ G_g,
                                              float* __restrict__ rowabs,
                                              int* __restrict__ scnt,
                                              int* __restrict__ dcnt) {
    __shared__ float WTs[6400];
    int tid = threadIdx.x;
    for (int e = tid; e < 6400; e += 256) WTs[e] = WT[e];
    __syncthreads();
    int e = blockIdx.x * 256 + tid;
    int k = e >> 6, l = e & 63;
    float a0 = 0, a1 = 0;
    #pragma unroll 10
    for (int c = 0; c < 100; c += 2) {
        a0 = fmaf(WTs[c * 64 + k],       WTs[c * 64 + l],       a0);
        a1 = fmaf(WTs[(c + 1) * 64 + k], WTs[(c + 1) * 64 + l], a1);
    }
    float g = (k == l) ? 0.0f : (a0 + a1);
    G_g[e] = g;
    float v = fabsf(g);
    for (int off = 32; off > 0; off >>= 1) v += __shfl_down(v, off, 64);
    if ((tid & 63) == 0) rowabs[k] = v;
    if (blockIdx.x == 0 && tid == 0) { *scnt = 0; *dcnt = 0; }
}

// ---------------- fast scan: B = sign(p), flag |p|<=rowabs columns ----------------
// EXACT for unflagged columns. track!=0 (pass 2): record changed columns for k_incr.
__global__ __launch_bounds__(256) void k_fast(const float* __restrict__ U,
                                              const float* __restrict__ u,
                                              const int* __restrict__ labelY,
                                              const int* __restrict__ ovr,
                                              const float* __restrict__ WT,
                                              const float* __restrict__ rowabs,
                                              u64* __restrict__ Bmask,
                                              int* __restrict__ slist,
                                              u64* __restrict__ sold,
                                              int* __restrict__ scnt,
                                              int track,
                                              int* __restrict__ dlist,
                                              u64* __restrict__ dold,
                                              int* __restrict__ dcnt) {
    __shared__ float WTs[100 * 65];   /* 65-pad: lane-varying c -> conflict-free */
    __shared__ float ra[64];
    int tid = threadIdx.x;
    for (int e = tid; e < 6400; e += 256)
        WTs[(e >> 6) * 65 + (e & 63)] = WT[e];
    if (tid < 64) ra[tid] = rowabs[tid] + SLACK;
    __syncthreads();
    int j = blockIdx.x * 256 + tid;
    if (j >= NTRAIN) return;
    int c = labelY[j], ov = ovr[j];
    const float* up; int str;
    if (ov) { up = u + (ov - 1) * NBIT; str = 1; }
    else    { up = U + j;               str = NTRAIN; }
    const float* wc = WTs + c * 65;
    u64 m = 0ull;
    int slow = 0;
    #pragma unroll
    for (int i = 0; i < NBIT; ++i) {
        float p = fmaf(ETA_MU, up[i * str], wc[i]);
        if (p > 0.0f) m |= (1ull << i);
        slow |= (fabsf(p) <= ra[i]);
    }
    if (slow) {
        int idx = atomicAdd(scnt, 1);
        if (idx < SCAP) { slist[idx] = j; sold[idx] = Bmask[j]; }
    }
    if (track) {
        u64 oldm = Bmask[j];
        if (m != oldm || slow) {
            int s2 = atomicAdd(dcnt, 1);
            dlist[s2] = j;
            dold[s2] = oldm;
        }
    }
    Bmask[j] = m;   // fallback for (impossible) list overflow; exact otherwise
}

// ---------------- wave-cooperative exact scan for flagged columns -------------
__global__ __launch_bounds__(1024) void k_slow(const int* __restrict__ slist,
                                               const u64* __restrict__ sold,
                                               const int* __restrict__ scnt,
                                               const int* __restrict__ labelY,
                                               const int* __restrict__ ovr,
                                               const float* __restrict__ G_g,
                                               const float* __restrict__ WT,
                                               const float* __restrict__ U,
                                               const float* __restrict__ u,
                                               u64* __restrict__ Bmask) {
    __shared__ float Gs[64 * 65];
    int tid = threadIdx.x, lane = tid & 63, wv = tid >> 6;   /* 16 waves */
    int n = *scnt; if (n > SCAP) n = SCAP;
    if (n == 0) return;
    for (int e = tid; e < 4096; e += 1024)
        Gs[(e >> 6) * 65 + (e & 63)] = G_g[e];
    __syncthreads();
    for (int idx = wv; idx < n; idx += 16) {
        int j = slist[idx];
        u64 m0 = sold[idx];
        int c = labelY[j], ov = ovr[j];
        float uval = ov ? u[(ov - 1) * NBIT + lane]
                        : U[(size_t)lane * NTRAIN + j];
        float p = fmaf(ETA_MU, uval, WT[c * 64 + lane]);
        float s = ((m0 >> lane) & 1ull) ? 1.0f : -1.0f;
        for (int i = 0; i < 64; ++i) {
            float t = Gs[i * 65 + lane] * s;   /* G[i,i]=0 -> self term drops */
            t += __shfl_xor(t, 1);  t += __shfl_xor(t, 2);
            t += __shfl_xor(t, 4);  t += __shfl_xor(t, 8);
            t += __shfl_xor(t, 16); t += __shfl_xor(t, 32);
            float nv = ((p - t) > 0.0f) ? 1.0f : -1.0f;
            s = (lane == i) ? nv : s;
        }
        u64 mo = __ballot(s > 0.0f);
        if (lane == 0) Bmask[j] = mo;
    }
}

// ---------------- likelihood via MFMA (the dot-product IS a GEMM) -------------
__global__ __launch_bounds__(256) void k_likm(const float* __restrict__ U,
                                              const float* __restrict__ u,
                                              const int* __restrict__ labelY,
                                              const int* __restrict__ ovr,
                                              const int* __restrict__ ylab,
                                              float* __restrict__ partials) {
    __shared__ short ubf[128 * 72];
    __shared__ int ylab_s[NBATCH];
    __shared__ float sbuf[8];
    int tid = threadIdx.x;
    for (int e = tid; e < NBATCH * NBIT; e += 256)
        ubf[(e >> 6) * 72 + (e & 63)] = f2bf(u[e]);
    if (tid < NBATCH) ylab_s[tid] = ylab[tid];
    __syncthreads();
    int w = tid >> 6, lane = tid & 63;
    int g = lane >> 4, c = lane & 15;
    int j = blockIdx.x * 64 + w * 16 + c;
    int jl = (j < NTRAIN) ? j : (NTRAIN - 1);
    int ov = ovr[jl];
    int lab = labelY[jl];
    const float* colp; int cstr;
    if (ov) { colp = u + (ov - 1) * NBIT; cstr = 1; }
    else    { colp = U + jl;              cstr = NTRAIN; }
    bf16x8 bf0, bf1;
    #pragma unroll
    for (int i = 0; i < 8; ++i) {
        bf0[i] = f2bf(colp[(g * 8 + i) * cstr]);
        bf1[i] = f2bf(colp[(32 + g * 8 + i) * cstr]);
    }
    float acc = 0.0f;
    #pragma unroll
    for (int bt = 0; bt < 8; ++bt) {
        bf16x8 a0 = *reinterpret_cast<const bf16x8*>(&ubf[(bt * 16 + c) * 72 + g * 8]);
        bf16x8 a1 = *reinterpret_cast<const bf16x8*>(&ubf[(bt * 16 + c) * 72 + 32 + g * 8]);
        f32x4 d = {0.f, 0.f, 0.f, 0.f};
        d = __builtin_amdgcn_mfma_f32_16x16x32_bf16(a0, bf0, d, 0, 0, 0);
        d = __builtin_amdgcn_mfma_f32_16x16x32_bf16(a1, bf1, d, 0, 0, 0);
        #pragma unroll
        for (int r = 0; r < 4; ++r) {
            int b = bt * 16 + g * 4 + r;
            float ipv = 0.5f * d[r];
            float aip = fabsf(ipv);
            float t = __logf(1.0f + __expf(-aip)) + fmaxf(ipv, 0.0f);
            if (ylab_s[b] == lab) t -= ipv;
            acc += t;
        }
    }
    if (j >= NTRAIN) acc = 0.0f;
    float tot = blk_reduce_sum(acc, sbuf);
    if (tid == 0) partials[blockIdx.x] = tot;
}

// ---------------- cl-loss, parallel: one thread per (c,b) element -------------
__global__ __launch_bounds__(256) void k_cl(const float* __restrict__ WT,
                                            const u64* __restrict__ Bmask,
                                            const int* __restrict__ ind,
                                            const float* __restrict__ y,
                                            float* __restrict__ clp) {
    __shared__ float sbuf[8];
    __shared__ u64 mB[NBATCH];
    int tid = threadIdx.x;
    if (tid < NBATCH) mB[tid] = Bmask[ind[tid]];
    __syncthreads();
    int e = blockIdx.x * 256 + tid;       /* e < 12800 exactly */
    int b = e & 127, c = e >> 7;
    u64 m = mB[b];
    const float4* __restrict__ wr = (const float4*)(WT + c * 64);
    float d0 = 0.f, d1 = 0.f, d2 = 0.f, d3 = 0.f;
    #pragma unroll
    for (int q = 0; q < 16; ++q) {
        float4 w4 = wr[q];
        int kb = q << 2;
        d0 += ((m >> kb) & 1ull)       ? w4.x : -w4.x;
        d1 += ((m >> (kb + 1)) & 1ull) ? w4.y : -w4.y;
        d2 += ((m >> (kb + 2)) & 1ull) ? w4.z : -w4.z;
        d3 += ((m >> (kb + 3)) & 1ull) ? w4.w : -w4.w;
    }
    float d = (d0 + d1) + (d2 + d3);
    float diff = y[b * NCLASS + c] - d;
    float tot = blk_reduce_sum(diff * diff, sbuf);
    if (tid == 0) clp[blockIdx.x] = tot;
}

// ---------------- final combine: lik partials + cl partials + reg loss --------
__global__ void k_fin(const float* __restrict__ WT,
                      const float* __restrict__ likp,
                      const float* __restrict__ clp,
                      float* __restrict__ out) {
    __shared__ float sbuf[8];
    int tid = threadIdx.x;
    float a = 0.f;
    for (int i = tid; i < NLIKB; i += 256) a += likp[i];
    float cl = 0.f;
    for (int i = tid; i < NCLB; i += 256) cl += clp[i];
    float rg = 0.f;
    for (int e = tid; e < NBIT * NCLASS; e += 256) {
        float w = WT[e];
        rg = fmaf(w, w, rg);
    }
    float lik = blk_reduce_sum(a, sbuf);
    float clS = blk_reduce_sum(cl, sbuf);
    float rgS = blk_reduce_sum(rg, sbuf);
    if (tid == 0) {
        out[0] = lik * (1.0f / ((float)NBATCH * (float)NTRAIN))
               + clS * (1.0f / (float)(NCLASS * NBATCH))
               + rgS * (1.0f / (float)(NBIT * NCLASS));
    }
}

extern "C" void kernel_launch(void* const* d_in, const int* in_sizes, int n_in,
                              void* d_out, int out_size, void* d_ws, size_t ws_size,
                              hipStream_t stream) {
    const float* u   = (const float*)d_in[0];
    const float* y   = (const float*)d_in[1];
    const float* U   = (const float*)d_in[2];
    const float* B   = (const float*)d_in[3];
    const float* Y   = (const float*)d_in[4];
    const int*   ind = (const int*)d_in[5];

    char* ws = (char*)d_ws;
    u64*   Bmask  = (u64*)(ws + OFF_BMASK);
    u64*   cmask  = (u64*)(ws + OFF_CMASK);
    u64*   planes = (u64*)(ws + OFF_PLANES);
    int*   labelY = (int*)(ws + OFF_LABELY);
    int*   ovr    = (int*)(ws + OFF_OVR);
    int*   ylab   = (int*)(ws + OFF_YLAB);
    int*   ccount = (int*)(ws + OFF_CCOUNT);
    float* A_f    = (float*)(ws + OFF_AF);
    float* RHS_f  = (float*)(ws + OFF_RHS);
    float* W      = (float*)(ws + OFF_W);
    float* WT     = (float*)(ws + OFF_WT);
    float* G      = (float*)(ws + OFF_G);
    float* rowabs = (float*)(ws + OFF_ROWABS);
    int*   scnt   = (int*)(ws + OFF_SCNT);
    int*   slist  = (int*)(ws + OFF_SLIST);
    u64*   sold   = (u64*)(ws + OFF_SOLD);
    int*   iAint  = (int*)(ws + OFF_IAI);
    int*   iBint  = (int*)(ws + OFF_IBI);
    int*   dcnt   = (int*)(ws + OFF_DCNT);
    int*   dlist  = (int*)(ws + OFF_DLIST);
    u64*   dold   = (u64*)(ws + OFF_DOLD);
    float* likp   = (float*)(ws + OFF_LIKP);
    float* clp    = (float*)(ws + OFF_CLP);

    hipMemsetAsync(ovr, 0, NTRAIN * sizeof(int), stream);
    hipMemsetAsync(dcnt, 0, sizeof(int), stream);

    k_scatter<<<1, 128, 0, stream>>>(y, ind, ovr, ylab, ccount);
    k_prep   <<<NBLK, 256, 0, stream>>>(Y, B, ovr, ylab, labelY, Bmask, cmask, ccount);

    // pass 1 (track=0) and pass 2 (track=1): full BBT/BYT via transpose + dot
    for (int pass = 0; pass < 2; ++pass) {
        k_trans  <<<NBLK, 256, 0, stream>>>(Bmask, planes);
        k_dot    <<<NDOTB, 1024, 0, stream>>>(planes, cmask, ccount,
                                              A_f, RHS_f, iAint, iBint);
        k_wsolve <<<25, 256, 0, stream>>>(A_f, RHS_f, W, WT);
        k_gram   <<<16, 256, 0, stream>>>(WT, G, rowabs, scnt, dcnt);
        k_fast   <<<NBLK, 256, 0, stream>>>(U, u, labelY, ovr, WT, rowabs,
                                            Bmask, slist, sold, scnt,
                                            pass, dlist, dold, dcnt);
        k_slow   <<<1, 1024, 0, stream>>>(slist, sold, scnt, labelY, ovr,
                                          G, WT, U, u, Bmask);
    }

    // pass 3: incremental A/RHS from pass-2's deltas (replaces trans+dot)
    k_incr  <<<41, 256, 0, stream>>>(dcnt, dlist, dold, Bmask, labelY,
                                     iAint, iBint, ccount, A_f, RHS_f);
    k_wsolve<<<25, 256, 0, stream>>>(A_f, RHS_f, W, WT);
    k_gram  <<<16, 256, 0, stream>>>(WT, G, rowabs, scnt, dcnt);
    k_fast  <<<NBLK, 256, 0, stream>>>(U, u, labelY, ovr, WT, rowabs,
                                       Bmask, slist, sold, scnt,
                                       0, dlist, dold, dcnt);
    k_slow  <<<1, 1024, 0, stream>>>(slist, sold, scnt, labelY, ovr,
                                     G, WT, U, u, Bmask);

    k_likm <<<NLIKB, 256, 0, stream>>>(U, u, labelY, ovr, ylab, likp);
    k_cl   <<<NCLB, 256, 0, stream>>>(WT, Bmask, ind, y, clp);
    k_fin  <<<1, 256, 0, stream>>>(WT, likp, clp, (float*)d_out);
}